// Round 8
// baseline (265.758 us; speedup 1.0000x reference)
//
#include <hip/hip_runtime.h>
#include <hip/hip_fp16.h>

// GraphSAGE 2-layer: logits = meanAgg(relu(meanAgg(x@W1)) @ W2)
// N=100000, E=1600000, D_IN=128, D_H=128, D_OUT=64, fp32 in/out.
//
// R2-R8: scan/CSR/bf16 ladder. R9: MFMA gemms. R10: dwordx4 gathers.
// R11: FAILED shfl-in-divergent-branch. R12: wave-uniform shfl.
// R13: flat gather tiers (neutral -> not issue-depth bound).
// R14: fp8 h1: FETCH 181->85MB but SLOWER (24 VALU/uint4 unpack).
// R15: fp16+pk_add: VALU 60->42% busy, time FLAT -> agg1 is pinned by the
//      L2-miss fetch path (~3.8 TB/s random-row). Bytes are the only lever.
// R17: fp8 h1 REVISITED with cheap unpack: cvt_pk_f32_fp8 returns float2,
//      accumulate with packed v_pk_add_f32 (16 ops/uint4, f32 numerics
//      identical to R14's proven absmax 0.0117), float2 reduce. h2 stays
//      fp16 (more precise than R14's bf16 -> combined error <= R14).
//      Expected: fetch 85MB (~22us) + ~26us VALU overlapped -> ~36-42us.

#define DIN 128
#define DH 128
#define DOUT 64

#define BSH 9                    // 512 rows per bucket
#define COLB 17                  // col fits 17 bits (N=100000 < 2^17)
#define COLM ((1 << COLB) - 1)
#define LRM ((1 << BSH) - 1)
#define CHUNK 4096               // edges per hist/part block
#define CH_PT 16                 // edges per thread

typedef __attribute__((ext_vector_type(8))) short short8;
typedef __attribute__((ext_vector_type(8))) _Float16 half8;
typedef __attribute__((ext_vector_type(4))) float floatx4;
typedef __attribute__((ext_vector_type(2))) float fx2;

__device__ __forceinline__ unsigned bfpack(float a, float b) {
    unsigned ua = __float_as_uint(a);
    unsigned ub = __float_as_uint(b);
    ua += 0x7fffu + ((ua >> 16) & 1u);
    ub += 0x7fffu + ((ub >> 16) & 1u);
    return (ua >> 16) | (ub & 0xffff0000u);
}
__device__ __forceinline__ unsigned short bf1(float a) {
    unsigned u = __float_as_uint(a);
    u += 0x7fffu + ((u >> 16) & 1u);
    return (unsigned short)(u >> 16);
}
// fp8 e4m3 encode (1 byte) via HW packed convert (proven R14)
__device__ __forceinline__ unsigned char f8enc(float v) {
    return (unsigned char)(__builtin_amdgcn_cvt_pk_fp8_f32(v, v, 0, false) & 0xff);
}

// packed-fp16 accumulate: one uint4 = 8 fp16, 4 v_pk_add_f16
__device__ __forceinline__ void acch2(__half2* a, uint4 v) {
    a[0] = __hadd2(a[0], *(const __half2*)&v.x);
    a[1] = __hadd2(a[1], *(const __half2*)&v.y);
    a[2] = __hadd2(a[2], *(const __half2*)&v.z);
    a[3] = __hadd2(a[3], *(const __half2*)&v.w);
}
__device__ __forceinline__ __half2 h2shfl_xor(__half2 v, int m) {
    int u = __shfl_xor(*(int*)&v, m);
    return *(__half2*)&u;
}
__device__ __forceinline__ unsigned h2bits(__half2 v) {
    return *(unsigned*)&v;
}
__device__ __forceinline__ __half2 h2zero() {
    unsigned z = 0u;
    return *(__half2*)&z;
}

// fp8 accumulate: one uint4 = 16 fp8 -> 8 cvt_pk_f32_fp8 (float2 each) +
// 8 packed f32 adds (v_pk_add_f32). f32 accumulation = R14 numerics.
__device__ __forceinline__ void accf8v(fx2* a, uint4 v) {
    a[0] += __builtin_amdgcn_cvt_pk_f32_fp8((int)v.x, false);
    a[1] += __builtin_amdgcn_cvt_pk_f32_fp8((int)v.x, true);
    a[2] += __builtin_amdgcn_cvt_pk_f32_fp8((int)v.y, false);
    a[3] += __builtin_amdgcn_cvt_pk_f32_fp8((int)v.y, true);
    a[4] += __builtin_amdgcn_cvt_pk_f32_fp8((int)v.z, false);
    a[5] += __builtin_amdgcn_cvt_pk_f32_fp8((int)v.z, true);
    a[6] += __builtin_amdgcn_cvt_pk_f32_fp8((int)v.w, false);
    a[7] += __builtin_amdgcn_cvt_pk_f32_fp8((int)v.w, true);
}
__device__ __forceinline__ fx2 fx2shfl_xor(fx2 v, int m) {
    fx2 r;
    r.x = __shfl_xor(v.x, m);
    r.y = __shfl_xor(v.y, m);
    return r;
}

// ---------------- weight prep: fp32 [k][n] -> bf16/fp16 [n][k] ----------
__global__ __launch_bounds__(256) void k_prep(const float* __restrict__ W1,
                                              const float* __restrict__ W2,
                                              unsigned short* __restrict__ Wt1,
                                              unsigned short* __restrict__ Wt2) {
    int idx = blockIdx.x * 256 + threadIdx.x;
    if (idx < 128 * 128) {
        int k = idx >> 7, nn = idx & 127;
        Wt1[nn * 128 + k] = bf1(W1[idx]);          // bf16 for gemm1
    }
    int i2 = idx - 128 * 128;
    if (i2 >= 0 && i2 < 128 * 64) {
        int k = i2 >> 6, nn = i2 & 63;
        Wt2[nn * 128 + k] = __half_as_ushort(__float2half(W2[i2]));  // fp16
    }
}

// ---------------- CSR build (counting sort) ----------------

__global__ __launch_bounds__(256) void k_hist(const int* __restrict__ row,
                                              int* __restrict__ HT,
                                              int E, int nb, int nch) {
    __shared__ int h[512];
    int t = threadIdx.x, c = blockIdx.x;
    for (int i = t; i < nb; i += 256) h[i] = 0;
    __syncthreads();
    int base = c * CHUNK;
#pragma unroll
    for (int i = 0; i < CH_PT; ++i) {
        int e = base + i * 256 + t;
        if (e < E) atomicAdd(&h[row[e] >> BSH], 1);
    }
    __syncthreads();
    for (int i = t; i < nb; i += 256) HT[(size_t)i * nch + c] = h[i];
}

__global__ __launch_bounds__(256) void k_hscan_row(int* __restrict__ HT,
                                                   int* __restrict__ bsum,
                                                   int nch) {
    __shared__ int sh[256];
    int b = blockIdx.x, t = threadIdx.x;
    int carry = 0;
    for (int tile = 0; tile < nch; tile += 256) {
        int idx = tile + t;
        int v = (idx < nch) ? HT[(size_t)b * nch + idx] : 0;
        sh[t] = v;
        __syncthreads();
        for (int d = 1; d < 256; d <<= 1) {
            int u = (t >= d) ? sh[t - d] : 0;
            __syncthreads();
            sh[t] += u;
            __syncthreads();
        }
        if (idx < nch) HT[(size_t)b * nch + idx] = carry + sh[t] - v;
        carry += sh[255];
        __syncthreads();
    }
    if (t == 0) bsum[b] = carry;
}

__global__ __launch_bounds__(256) void k_hscan_base(const int* __restrict__ bsum,
                                                    int* __restrict__ bucketBase,
                                                    int nb, int E) {
    __shared__ int sh[256];
    int t = threadIdx.x;
    int v = (t < nb) ? bsum[t] : 0;
    sh[t] = v;
    __syncthreads();
    for (int d = 1; d < 256; d <<= 1) {
        int u = (t >= d) ? sh[t - d] : 0;
        __syncthreads();
        sh[t] += u;
        __syncthreads();
    }
    if (t < nb) bucketBase[t] = sh[t] - v;
    if (t == 0) bucketBase[nb] = E;
}

__global__ __launch_bounds__(256) void k_part(const int* __restrict__ row,
                                              const int* __restrict__ col,
                                              const int* __restrict__ HT,
                                              const int* __restrict__ bucketBase,
                                              int* __restrict__ packed,
                                              int E, int nb, int nch) {
    __shared__ int cur[512];
    int t = threadIdx.x, c = blockIdx.x;
    for (int i = t; i < nb; i += 256)
        cur[i] = HT[(size_t)i * nch + c] + bucketBase[i];
    __syncthreads();
    int base = c * CHUNK;
#pragma unroll
    for (int i = 0; i < CH_PT; ++i) {
        int e = base + i * 256 + t;
        if (e < E) {
            int r = row[e], cc = col[e];
            int b = r >> BSH;
            int pos = atomicAdd(&cur[b], 1);
            packed[pos] = ((r & LRM) << COLB) | cc;
        }
    }
}

__global__ __launch_bounds__(256) void k_build(const int* __restrict__ packed,
                                               const int* __restrict__ bucketBase,
                                               int* __restrict__ csr,
                                               int* __restrict__ offs,
                                               int* __restrict__ degc,
                                               float* __restrict__ invdeg,
                                               int N, int nb) {
    __shared__ int hist[512], scn[512], part[256];
    int t = threadIdx.x, b = blockIdx.x;
    int lo = bucketBase[b], hi = bucketBase[b + 1];
    int base_row = b << BSH;
    int nloc = N - base_row; if (nloc > 512) nloc = 512;
    hist[t] = 0; hist[t + 256] = 0;
    __syncthreads();
    for (int e = lo + t; e < hi; e += 256)
        atomicAdd(&hist[packed[e] >> COLB], 1);
    __syncthreads();
    int a = hist[2 * t], b2 = hist[2 * t + 1];
    part[t] = a + b2;
    __syncthreads();
    for (int d = 1; d < 256; d <<= 1) {
        int v = (t >= d) ? part[t - d] : 0;
        __syncthreads();
        part[t] += v;
        __syncthreads();
    }
    int bp = (t == 0) ? 0 : part[t - 1];
    scn[2 * t] = bp;
    scn[2 * t + 1] = bp + a;
    __syncthreads();
    for (int i = t; i < nloc; i += 256) {
        int r = base_row + i;
        offs[r] = lo + scn[i];
        int d = hist[i];
        degc[r] = d;
        invdeg[r] = 1.0f / (float)d;
    }
    __syncthreads();
    for (int e = lo + t; e < hi; e += 256) {
        int p = packed[e];
        int pos = lo + atomicAdd(&scn[p >> COLB], 1);
        csr[pos] = p & COLM;
    }
}

// ---------------- MFMA GEMMs ----------------

// h1f8[n,128](fp8 e4m3) = X @ W1 (bf16 MFMA, fp8 store). 64-row block.
__global__ __launch_bounds__(256) void k_gemm1(const float* __restrict__ X,
                                               const unsigned short* __restrict__ Wt,
                                               unsigned char* __restrict__ H1f8, int n) {
    __shared__ unsigned short xs[64][136];    // pitch 272B: 2-way-bank-safe b128
    __shared__ unsigned short wt[128][136];
    int tid = threadIdx.x;
    int r0 = blockIdx.x * 64;

    for (int i = tid; i < 64 * 32; i += 256) {
        int r = i >> 5, c4 = i & 31;
        float4 v = make_float4(0.f, 0.f, 0.f, 0.f);
        if (r0 + r < n) v = ((const float4*)X)[(size_t)(r0 + r) * 32 + c4];
        *(uint2*)&xs[r][c4 * 4] = make_uint2(bfpack(v.x, v.y), bfpack(v.z, v.w));
    }
    for (int i = tid; i < 128 * 16; i += 256) {
        int r = i >> 4, c = i & 15;
        *(uint4*)&wt[r][c * 8] = ((const uint4*)Wt)[r * 16 + c];
    }
    __syncthreads();

    int w = tid >> 6, lane = tid & 63;
    int ml = lane & 15, q = lane >> 4;
    floatx4 acc[8];
#pragma unroll
    for (int t = 0; t < 8; ++t) acc[t] = (floatx4)(0.f);

#pragma unroll
    for (int kc = 0; kc < 4; ++kc) {
        short8 af = *(const short8*)&xs[w * 16 + ml][kc * 32 + q * 8];
#pragma unroll
        for (int nt = 0; nt < 8; ++nt) {
            short8 bf = *(const short8*)&wt[nt * 16 + ml][kc * 32 + q * 8];
            acc[nt] = __builtin_amdgcn_mfma_f32_16x16x32_bf16(af, bf, acc[nt], 0, 0, 0);
        }
    }
#pragma unroll
    for (int nt = 0; nt < 8; ++nt)
#pragma unroll
        for (int r = 0; r < 4; ++r) {
            int rr = r0 + w * 16 + q * 4 + r;
            if (rr < n)
                H1f8[(size_t)rr * 128 + nt * 16 + ml] = f8enc(acc[nt][r]);
        }
}

// h2h[n,64](fp16) = h(fp16) @ W2 (f16 MFMA). Same structure, N=64.
__global__ __launch_bounds__(256) void k_gemm2(const unsigned* __restrict__ Hin,
                                               const unsigned short* __restrict__ Wt,
                                               unsigned short* __restrict__ H2h, int n) {
    __shared__ unsigned short xs[64][136];
    __shared__ unsigned short wt[64][136];
    int tid = threadIdx.x;
    int r0 = blockIdx.x * 64;

    for (int i = tid; i < 64 * 16; i += 256) {
        int r = i >> 4, c = i & 15;
        uint4 v = make_uint4(0u, 0u, 0u, 0u);
        if (r0 + r < n) v = ((const uint4*)Hin)[(size_t)(r0 + r) * 16 + c];
        *(uint4*)&xs[r][c * 8] = v;
    }
    for (int i = tid; i < 64 * 16; i += 256) {
        int r = i >> 4, c = i & 15;
        *(uint4*)&wt[r][c * 8] = ((const uint4*)Wt)[r * 16 + c];
    }
    __syncthreads();

    int w = tid >> 6, lane = tid & 63;
    int ml = lane & 15, q = lane >> 4;
    floatx4 acc[4];
#pragma unroll
    for (int t = 0; t < 4; ++t) acc[t] = (floatx4)(0.f);

#pragma unroll
    for (int kc = 0; kc < 4; ++kc) {
        half8 af = *(const half8*)&xs[w * 16 + ml][kc * 32 + q * 8];
#pragma unroll
        for (int nt = 0; nt < 4; ++nt) {
            half8 bf = *(const half8*)&wt[nt * 16 + ml][kc * 32 + q * 8];
            acc[nt] = __builtin_amdgcn_mfma_f32_16x16x32_f16(af, bf, acc[nt], 0, 0, 0);
        }
    }
#pragma unroll
    for (int nt = 0; nt < 4; ++nt)
#pragma unroll
        for (int r = 0; r < 4; ++r) {
            int rr = r0 + w * 16 + q * 4 + r;
            if (rr < n)
                H2h[(size_t)rr * 64 + nt * 16 + ml] =
                    __half_as_ushort(__float2half(acc[nt][r]));
        }
}

// ---------------- Aggregations ----------------

// agg1: h[row](fp16) = relu((1/deg) * sum h1f8[c]), fp8 rows of 128B =
// 8 uint4. 8 lanes per neighbor row (sl = lane&7), g = lane>>3 -> 8
// neighbors per dwordx4 gather; tiers of 2 slots (16 nbrs), d wave-uniform.
// Accumulate: cvt_pk_f32_fp8 -> float2, packed v_pk_add_f32 (16 ops/uint4,
// f32 numerics = R14's proven absmax). float2 reduce, 3 rounds.
#define AF_SLOT(vv, s)                                                      \
    {                                                                       \
        int j = (s) * 8 + g;                                                \
        int c = __shfl(idx, (j < nd) ? j : 0);                              \
        vv = make_uint4(0u, 0u, 0u, 0u);                                    \
        if (j < nd) vv = H1f8[((unsigned)c << 3) + sl];                     \
    }

__global__ __launch_bounds__(256) void k_agg1(const uint4* __restrict__ H1f8,
                                              const int* __restrict__ offs,
                                              const int* __restrict__ degc,
                                              const float* __restrict__ invdeg,
                                              const int* __restrict__ csr,
                                              uint4* __restrict__ Hout, int n) {
    int wave = threadIdx.x >> 6, lane = threadIdx.x & 63;
    int row = blockIdx.x * 4 + wave;
    if (row >= n) return;
    int start = offs[row], d = degc[row];
    float inv = invdeg[row];
    int g = lane >> 3;       // neighbor slot 0..7
    int sl = lane & 7;       // 16B segment within 128B fp8 row

    int nd = d < 64 ? d : 64;
    int idx = (lane < nd) ? csr[start + lane] : 0;

    fx2 acc[8];
#pragma unroll
    for (int k = 0; k < 8; ++k) acc[k] = (fx2)(0.f);

    uint4 v0, v1;
    AF_SLOT(v0, 0) AF_SLOT(v1, 1)
    accf8v(acc, v0); accf8v(acc, v1);
    if (nd > 16) {
        AF_SLOT(v0, 2) AF_SLOT(v1, 3)
        accf8v(acc, v0); accf8v(acc, v1);
    }
    if (nd > 32) {
        AF_SLOT(v0, 4) AF_SLOT(v1, 5)
        accf8v(acc, v0); accf8v(acc, v1);
    }
    if (nd > 48) {
        AF_SLOT(v0, 6) AF_SLOT(v1, 7)
        accf8v(acc, v0); accf8v(acc, v1);
    }
    if (d > 64) {                    // rare fallback
        for (int i = 64; i < d; i += 8) {
            int j = i + g;
            uint4 v = make_uint4(0u, 0u, 0u, 0u);
            if (j < d) {
                int c = csr[start + j];
                v = H1f8[((unsigned)c << 3) + sl];
            }
            accf8v(acc, v);
        }
    }

#pragma unroll
    for (int k = 0; k < 8; ++k) {
        acc[k] += fx2shfl_xor(acc[k], 8);
        acc[k] += fx2shfl_xor(acc[k], 16);
        acc[k] += fx2shfl_xor(acc[k], 32);
    }

    if (g == 0) {
        float f[16];
#pragma unroll
        for (int k = 0; k < 8; ++k) {
            f[2 * k]     = fmaxf(acc[k].x * inv, 0.f);
            f[2 * k + 1] = fmaxf(acc[k].y * inv, 0.f);
        }
        uint4 o0, o1;
        o0.x = h2bits(__floats2half2_rn(f[0], f[1]));
        o0.y = h2bits(__floats2half2_rn(f[2], f[3]));
        o0.z = h2bits(__floats2half2_rn(f[4], f[5]));
        o0.w = h2bits(__floats2half2_rn(f[6], f[7]));
        o1.x = h2bits(__floats2half2_rn(f[8], f[9]));
        o1.y = h2bits(__floats2half2_rn(f[10], f[11]));
        o1.z = h2bits(__floats2half2_rn(f[12], f[13]));
        o1.w = h2bits(__floats2half2_rn(f[14], f[15]));
        Hout[(size_t)row * 16 + sl * 2]     = o0;
        Hout[(size_t)row * 16 + sl * 2 + 1] = o1;
    }
}

// agg2: Out[row](fp32) = (1/deg) * sum h2h[c], D=64 (row = 8 uint4, fp16).
// 8-lane groups, packed-fp16 accumulate, 3-round reduce on 4 regs.
#define A2_SLOT(vv, s)                                                      \
    {                                                                       \
        int j = (s) * 8 + g;                                                \
        int c = __shfl(idx, (j < nd) ? j : 0);                              \
        vv = make_uint4(0u, 0u, 0u, 0u);                                    \
        if (j < nd) vv = H2h[((unsigned)c << 3) + sl];                      \
    }

__global__ __launch_bounds__(256) void k_agg2(const uint4* __restrict__ H2h,
                                              const int* __restrict__ offs,
                                              const int* __restrict__ degc,
                                              const float* __restrict__ invdeg,
                                              const int* __restrict__ csr,
                                              float* __restrict__ Out, int n) {
    int wave = threadIdx.x >> 6, lane = threadIdx.x & 63;
    int row = blockIdx.x * 4 + wave;
    if (row >= n) return;
    int start = offs[row], d = degc[row];
    float inv = invdeg[row];
    int g = lane >> 3;       // neighbor slot 0..7
    int sl = lane & 7;       // 16B segment within 128B fp16 row

    int nd = d < 64 ? d : 64;
    int idx = (lane < nd) ? csr[start + lane] : 0;

    __half2 acc[4];
#pragma unroll
    for (int k = 0; k < 4; ++k) acc[k] = h2zero();

    uint4 v0, v1;
    A2_SLOT(v0, 0) A2_SLOT(v1, 1)
    acch2(acc, v0); acch2(acc, v1);
    if (nd > 16) {
        A2_SLOT(v0, 2) A2_SLOT(v1, 3)
        acch2(acc, v0); acch2(acc, v1);
    }
    if (nd > 32) {
        A2_SLOT(v0, 4) A2_SLOT(v1, 5)
        acch2(acc, v0); acch2(acc, v1);
    }
    if (nd > 48) {
        A2_SLOT(v0, 6) A2_SLOT(v1, 7)
        acch2(acc, v0); acch2(acc, v1);
    }
    if (d > 64) {                    // rare fallback
        for (int i = 64; i < d; i += 8) {
            int j = i + g;
            uint4 v = make_uint4(0u, 0u, 0u, 0u);
            if (j < d) {
                int c = csr[start + j];
                v = H2h[((unsigned)c << 3) + sl];
            }
            acch2(acc, v);
        }
    }

#pragma unroll
    for (int k = 0; k < 4; ++k) {
        acc[k] = __hadd2(acc[k], h2shfl_xor(acc[k], 8));
        acc[k] = __hadd2(acc[k], h2shfl_xor(acc[k], 16));
        acc[k] = __hadd2(acc[k], h2shfl_xor(acc[k], 32));
    }

    if (g == 0) {
        float4 o0, o1;
        o0.x = __low2float(acc[0]) * inv;  o0.y = __high2float(acc[0]) * inv;
        o0.z = __low2float(acc[1]) * inv;  o0.w = __high2float(acc[1]) * inv;
        o1.x = __low2float(acc[2]) * inv;  o1.y = __high2float(acc[2]) * inv;
        o1.z = __low2float(acc[3]) * inv;  o1.w = __high2float(acc[3]) * inv;
        ((float4*)Out)[(size_t)row * 16 + sl * 2]     = o0;
        ((float4*)Out)[(size_t)row * 16 + sl * 2 + 1] = o1;
    }
}

extern "C" void kernel_launch(void* const* d_in, const int* in_sizes, int n_in,
                              void* d_out, int out_size, void* d_ws, size_t ws_size,
                              hipStream_t stream) {
    const float* x    = (const float*)d_in[0];
    const float* W1   = (const float*)d_in[1];
    const float* W2   = (const float*)d_in[2];
    const int*   erow = (const int*)d_in[3];
    const int*   ecol = (const int*)d_in[4];
    const int N = in_sizes[0] / DIN;
    const int E = in_sizes[3];

    const int nb  = (N + (1 << BSH) - 1) >> BSH;   // 196 buckets
    const int nch = (E + CHUNK - 1) / CHUNK;       // 391 chunks

    size_t o = 0;
    auto take = [&](size_t nbytes) {
        void* p = (char*)d_ws + o;
        o += (nbytes + 255) & ~(size_t)255;
        return p;
    };
    int*            HT     = (int*)take((size_t)nb * nch * 4);
    int*            bsum   = (int*)take((size_t)nb * 4);
    int*            bbase  = (int*)take((size_t)(nb + 1) * 4);
    int*            packed = (int*)take((size_t)E * 4);
    int*            csr    = (int*)take((size_t)E * 4);
    int*            offs   = (int*)take((size_t)N * 4);
    int*            degc   = (int*)take((size_t)N * 4);
    float*          invdeg = (float*)take((size_t)N * 4);
    unsigned short* Wt1    = (unsigned short*)take(128 * 128 * 2);
    unsigned short* Wt2    = (unsigned short*)take(64 * 128 * 2);
    unsigned char*  h1f8   = (unsigned char*)take((size_t)N * DH);      // fp8
    unsigned*       h      = (unsigned*)take((size_t)N * DH * 2);       // fp16
    unsigned short* h2h    = (unsigned short*)h1f8;  // reuse (dead after agg1)

    k_prep      <<<96,  256, 0, stream>>>(W1, W2, Wt1, Wt2);
    k_hist      <<<nch, 256, 0, stream>>>(erow, HT, E, nb, nch);
    k_hscan_row <<<nb,  256, 0, stream>>>(HT, bsum, nch);
    k_hscan_base<<<1,   256, 0, stream>>>(bsum, bbase, nb, E);
    k_part      <<<nch, 256, 0, stream>>>(erow, ecol, HT, bbase, packed, E, nb, nch);
    k_build     <<<nb,  256, 0, stream>>>(packed, bbase, csr, offs, degc, invdeg, N, nb);
    k_gemm1<<<(N + 63) / 64, 256, 0, stream>>>(x, Wt1, h1f8, N);
    k_agg1 <<<(N + 3) / 4, 256, 0, stream>>>((const uint4*)h1f8, offs, degc, invdeg,
                                             csr, (uint4*)h, N);
    k_gemm2<<<(N + 63) / 64, 256, 0, stream>>>(h, Wt2, h2h, N);
    k_agg2 <<<(N + 3) / 4, 256, 0, stream>>>((const uint4*)h2h, offs, degc,
                                             invdeg, csr, (float*)d_out, N);
}

// Round 9
// 265.131 us; speedup vs baseline: 1.0024x; 1.0024x over previous
//
#include <hip/hip_runtime.h>
#include <hip/hip_fp16.h>

// GraphSAGE 2-layer: logits = meanAgg(relu(meanAgg(x@W1)) @ W2)
// N=100000, E=1600000, D_IN=128, D_H=128, D_OUT=64, fp32 in/out.
//
// R2-R8: scan/CSR/bf16 ladder. R9: MFMA gemms. R10: dwordx4 gathers.
// R11: FAILED shfl-in-divergent-branch. R12: wave-uniform shfl.
// R13: flat gather tiers (neutral). R14: fp8 h1 slower (unpack VALU).
// R15: fp16 + packed v_pk_add_f16: agg1 56us, absmax 0.0039. Best agg1.
// R17: fp8 + pk_add_f32: fetch 85MB but 61.5us — the 48 ds_bpermute/wave
//      reduce (fx2 shfl x3 rounds x8 regs) serializes on the per-CU LDS
//      path. Conclusion: agg1 ~56us is structural; cross-lane ops price
//      the reduce, not fetch bytes.
// R18: revert agg1/gemm1 to R15 fp16 (proven 56us, 3x absmax margin) and
//      attack the never-profiled ~140us CSR-build chain: BSH 9->8 (k_build
//      196->391 blocks, halves per-block serial work), CHUNK 4096->2048
//      (hist/part 391->782 blocks). k_hscan_base rewritten for 512 entries.

#define DIN 128
#define DH 128
#define DOUT 64

#define BSH 8                    // 256 rows per bucket (R18: was 9)
#define COLB 17                  // col fits 17 bits (N=100000 < 2^17)
#define COLM ((1 << COLB) - 1)
#define LRM ((1 << BSH) - 1)
#define CHUNK 2048               // edges per hist/part block (R18: was 4096)
#define CH_PT 8                  // edges per thread

typedef __attribute__((ext_vector_type(8))) short short8;
typedef __attribute__((ext_vector_type(8))) _Float16 half8;
typedef __attribute__((ext_vector_type(4))) float floatx4;

__device__ __forceinline__ unsigned bfpack(float a, float b) {
    unsigned ua = __float_as_uint(a);
    unsigned ub = __float_as_uint(b);
    ua += 0x7fffu + ((ua >> 16) & 1u);
    ub += 0x7fffu + ((ub >> 16) & 1u);
    return (ua >> 16) | (ub & 0xffff0000u);
}
__device__ __forceinline__ unsigned short bf1(float a) {
    unsigned u = __float_as_uint(a);
    u += 0x7fffu + ((u >> 16) & 1u);
    return (unsigned short)(u >> 16);
}

// packed-fp16 accumulate: one uint4 = 8 fp16, 4 v_pk_add_f16
__device__ __forceinline__ void acch2(__half2* a, uint4 v) {
    a[0] = __hadd2(a[0], *(const __half2*)&v.x);
    a[1] = __hadd2(a[1], *(const __half2*)&v.y);
    a[2] = __hadd2(a[2], *(const __half2*)&v.z);
    a[3] = __hadd2(a[3], *(const __half2*)&v.w);
}
__device__ __forceinline__ __half2 h2shfl_xor(__half2 v, int m) {
    int u = __shfl_xor(*(int*)&v, m);
    return *(__half2*)&u;
}
__device__ __forceinline__ unsigned h2bits(__half2 v) {
    return *(unsigned*)&v;
}
__device__ __forceinline__ __half2 h2zero() {
    unsigned z = 0u;
    return *(__half2*)&z;
}

// ---------------- weight prep: fp32 [k][n] -> bf16/fp16 [n][k] ----------
__global__ __launch_bounds__(256) void k_prep(const float* __restrict__ W1,
                                              const float* __restrict__ W2,
                                              unsigned short* __restrict__ Wt1,
                                              unsigned short* __restrict__ Wt2) {
    int idx = blockIdx.x * 256 + threadIdx.x;
    if (idx < 128 * 128) {
        int k = idx >> 7, nn = idx & 127;
        Wt1[nn * 128 + k] = bf1(W1[idx]);          // bf16 for gemm1
    }
    int i2 = idx - 128 * 128;
    if (i2 >= 0 && i2 < 128 * 64) {
        int k = i2 >> 6, nn = i2 & 63;
        Wt2[nn * 128 + k] = __half_as_ushort(__float2half(W2[i2]));  // fp16
    }
}

// ---------------- CSR build (counting sort) ----------------

__global__ __launch_bounds__(256) void k_hist(const int* __restrict__ row,
                                              int* __restrict__ HT,
                                              int E, int nb, int nch) {
    __shared__ int h[512];
    int t = threadIdx.x, c = blockIdx.x;
    for (int i = t; i < nb; i += 256) h[i] = 0;
    __syncthreads();
    int base = c * CHUNK;
#pragma unroll
    for (int i = 0; i < CH_PT; ++i) {
        int e = base + i * 256 + t;
        if (e < E) atomicAdd(&h[row[e] >> BSH], 1);
    }
    __syncthreads();
    for (int i = t; i < nb; i += 256) HT[(size_t)i * nch + c] = h[i];
}

__global__ __launch_bounds__(256) void k_hscan_row(int* __restrict__ HT,
                                                   int* __restrict__ bsum,
                                                   int nch) {
    __shared__ int sh[256];
    int b = blockIdx.x, t = threadIdx.x;
    int carry = 0;
    for (int tile = 0; tile < nch; tile += 256) {
        int idx = tile + t;
        int v = (idx < nch) ? HT[(size_t)b * nch + idx] : 0;
        sh[t] = v;
        __syncthreads();
        for (int d = 1; d < 256; d <<= 1) {
            int u = (t >= d) ? sh[t - d] : 0;
            __syncthreads();
            sh[t] += u;
            __syncthreads();
        }
        if (idx < nch) HT[(size_t)b * nch + idx] = carry + sh[t] - v;
        carry += sh[255];
        __syncthreads();
    }
    if (t == 0) bsum[b] = carry;
}

// 512-thread scan (nb up to 512 buckets with BSH=8)
__global__ __launch_bounds__(512) void k_hscan_base(const int* __restrict__ bsum,
                                                    int* __restrict__ bucketBase,
                                                    int nb, int E) {
    __shared__ int sh[512];
    int t = threadIdx.x;
    int v = (t < nb) ? bsum[t] : 0;
    sh[t] = v;
    __syncthreads();
    for (int d = 1; d < 512; d <<= 1) {
        int u = (t >= d) ? sh[t - d] : 0;
        __syncthreads();
        sh[t] += u;
        __syncthreads();
    }
    if (t < nb) bucketBase[t] = sh[t] - v;
    if (t == 0) bucketBase[nb] = E;
}

__global__ __launch_bounds__(256) void k_part(const int* __restrict__ row,
                                              const int* __restrict__ col,
                                              const int* __restrict__ HT,
                                              const int* __restrict__ bucketBase,
                                              int* __restrict__ packed,
                                              int E, int nb, int nch) {
    __shared__ int cur[512];
    int t = threadIdx.x, c = blockIdx.x;
    for (int i = t; i < nb; i += 256)
        cur[i] = HT[(size_t)i * nch + c] + bucketBase[i];
    __syncthreads();
    int base = c * CHUNK;
#pragma unroll
    for (int i = 0; i < CH_PT; ++i) {
        int e = base + i * 256 + t;
        if (e < E) {
            int r = row[e], cc = col[e];
            int b = r >> BSH;
            int pos = atomicAdd(&cur[b], 1);
            packed[pos] = ((r & LRM) << COLB) | cc;
        }
    }
}

__global__ __launch_bounds__(256) void k_build(const int* __restrict__ packed,
                                               const int* __restrict__ bucketBase,
                                               int* __restrict__ csr,
                                               int* __restrict__ offs,
                                               int* __restrict__ degc,
                                               float* __restrict__ invdeg,
                                               int N, int nb) {
    __shared__ int hist[256], scn[256], part[256];
    int t = threadIdx.x, b = blockIdx.x;
    int lo = bucketBase[b], hi = bucketBase[b + 1];
    int base_row = b << BSH;
    int nloc = N - base_row; if (nloc > 256) nloc = 256;
    hist[t] = 0;
    __syncthreads();
    for (int e = lo + t; e < hi; e += 256)
        atomicAdd(&hist[packed[e] >> COLB], 1);
    __syncthreads();
    int a = hist[t];
    part[t] = a;
    __syncthreads();
    for (int d = 1; d < 256; d <<= 1) {
        int v = (t >= d) ? part[t - d] : 0;
        __syncthreads();
        part[t] += v;
        __syncthreads();
    }
    scn[t] = part[t] - a;              // exclusive scan
    __syncthreads();
    for (int i = t; i < nloc; i += 256) {
        int r = base_row + i;
        offs[r] = lo + scn[i];
        int d = hist[i];
        degc[r] = d;
        invdeg[r] = 1.0f / (float)d;
    }
    __syncthreads();
    for (int e = lo + t; e < hi; e += 256) {
        int p = packed[e];
        int pos = lo + atomicAdd(&scn[p >> COLB], 1);
        csr[pos] = p & COLM;
    }
}

// ---------------- MFMA GEMMs ----------------

// h1h[n,128](fp16) = X @ W1 (bf16 MFMA, fp16 store). 64-row block.
__global__ __launch_bounds__(256) void k_gemm1(const float* __restrict__ X,
                                               const unsigned short* __restrict__ Wt,
                                               unsigned short* __restrict__ H1h, int n) {
    __shared__ unsigned short xs[64][136];    // pitch 272B: 2-way-bank-safe b128
    __shared__ unsigned short wt[128][136];
    int tid = threadIdx.x;
    int r0 = blockIdx.x * 64;

    for (int i = tid; i < 64 * 32; i += 256) {
        int r = i >> 5, c4 = i & 31;
        float4 v = make_float4(0.f, 0.f, 0.f, 0.f);
        if (r0 + r < n) v = ((const float4*)X)[(size_t)(r0 + r) * 32 + c4];
        *(uint2*)&xs[r][c4 * 4] = make_uint2(bfpack(v.x, v.y), bfpack(v.z, v.w));
    }
    for (int i = tid; i < 128 * 16; i += 256) {
        int r = i >> 4, c = i & 15;
        *(uint4*)&wt[r][c * 8] = ((const uint4*)Wt)[r * 16 + c];
    }
    __syncthreads();

    int w = tid >> 6, lane = tid & 63;
    int ml = lane & 15, q = lane >> 4;
    floatx4 acc[8];
#pragma unroll
    for (int t = 0; t < 8; ++t) acc[t] = (floatx4)(0.f);

#pragma unroll
    for (int kc = 0; kc < 4; ++kc) {
        short8 af = *(const short8*)&xs[w * 16 + ml][kc * 32 + q * 8];
#pragma unroll
        for (int nt = 0; nt < 8; ++nt) {
            short8 bf = *(const short8*)&wt[nt * 16 + ml][kc * 32 + q * 8];
            acc[nt] = __builtin_amdgcn_mfma_f32_16x16x32_bf16(af, bf, acc[nt], 0, 0, 0);
        }
    }
#pragma unroll
    for (int nt = 0; nt < 8; ++nt)
#pragma unroll
        for (int r = 0; r < 4; ++r) {
            int rr = r0 + w * 16 + q * 4 + r;
            if (rr < n)
                H1h[(size_t)rr * 128 + nt * 16 + ml] =
                    __half_as_ushort(__float2half(acc[nt][r]));
        }
}

// h2h[n,64](fp16) = h(fp16) @ W2 (f16 MFMA). Same structure, N=64.
__global__ __launch_bounds__(256) void k_gemm2(const unsigned* __restrict__ Hin,
                                               const unsigned short* __restrict__ Wt,
                                               unsigned short* __restrict__ H2h, int n) {
    __shared__ unsigned short xs[64][136];
    __shared__ unsigned short wt[64][136];
    int tid = threadIdx.x;
    int r0 = blockIdx.x * 64;

    for (int i = tid; i < 64 * 16; i += 256) {
        int r = i >> 4, c = i & 15;
        uint4 v = make_uint4(0u, 0u, 0u, 0u);
        if (r0 + r < n) v = ((const uint4*)Hin)[(size_t)(r0 + r) * 16 + c];
        *(uint4*)&xs[r][c * 8] = v;
    }
    for (int i = tid; i < 64 * 16; i += 256) {
        int r = i >> 4, c = i & 15;
        *(uint4*)&wt[r][c * 8] = ((const uint4*)Wt)[r * 16 + c];
    }
    __syncthreads();

    int w = tid >> 6, lane = tid & 63;
    int ml = lane & 15, q = lane >> 4;
    floatx4 acc[4];
#pragma unroll
    for (int t = 0; t < 4; ++t) acc[t] = (floatx4)(0.f);

#pragma unroll
    for (int kc = 0; kc < 4; ++kc) {
        half8 af = *(const half8*)&xs[w * 16 + ml][kc * 32 + q * 8];
#pragma unroll
        for (int nt = 0; nt < 4; ++nt) {
            half8 bf = *(const half8*)&wt[nt * 16 + ml][kc * 32 + q * 8];
            acc[nt] = __builtin_amdgcn_mfma_f32_16x16x32_f16(af, bf, acc[nt], 0, 0, 0);
        }
    }
#pragma unroll
    for (int nt = 0; nt < 4; ++nt)
#pragma unroll
        for (int r = 0; r < 4; ++r) {
            int rr = r0 + w * 16 + q * 4 + r;
            if (rr < n)
                H2h[(size_t)rr * 64 + nt * 16 + ml] =
                    __half_as_ushort(__float2half(acc[nt][r]));
        }
}

// ---------------- Aggregations ----------------

// agg1: h[row](fp16) = relu((1/deg) * sum h1h[c]), D=128 (row = 16 uint4).
// R15 structure: csr row cached in regs, wave-uniform shfl distribution,
// unrolled tiers, packed-fp16 accumulate (4 inst/uint4), 2-round reduce.
#define A1_SLOT(vv, s)                                                      \
    {                                                                       \
        int j = (s) * 4 + g;                                                \
        int c = __shfl(idx, (j < nd) ? j : 0);                              \
        vv = make_uint4(0u, 0u, 0u, 0u);                                    \
        if (j < nd) vv = H1h[((unsigned)c << 4) + sl];                      \
    }

__global__ __launch_bounds__(256) void k_agg1(const uint4* __restrict__ H1h,
                                              const int* __restrict__ offs,
                                              const int* __restrict__ degc,
                                              const float* __restrict__ invdeg,
                                              const int* __restrict__ csr,
                                              uint4* __restrict__ Hout, int n) {
    int wave = threadIdx.x >> 6, lane = threadIdx.x & 63;
    int row = blockIdx.x * 4 + wave;
    if (row >= n) return;
    int start = offs[row], d = degc[row];
    float inv = invdeg[row];
    int g = lane >> 4;       // neighbor slot 0..3
    int sl = lane & 15;      // 16B segment within 256B fp16 row

    int nd = d < 64 ? d : 64;
    int idx = (lane < nd) ? csr[start + lane] : 0;

    __half2 acc[4];
#pragma unroll
    for (int k = 0; k < 4; ++k) acc[k] = h2zero();

    uint4 v0, v1, v2, v3;
    A1_SLOT(v0, 0) A1_SLOT(v1, 1) A1_SLOT(v2, 2) A1_SLOT(v3, 3)
    acch2(acc, v0); acch2(acc, v1); acch2(acc, v2); acch2(acc, v3);
    if (nd > 16) {
        A1_SLOT(v0, 4) A1_SLOT(v1, 5) A1_SLOT(v2, 6) A1_SLOT(v3, 7)
        acch2(acc, v0); acch2(acc, v1); acch2(acc, v2); acch2(acc, v3);
    }
    if (nd > 32) {
        A1_SLOT(v0, 8) A1_SLOT(v1, 9) A1_SLOT(v2, 10) A1_SLOT(v3, 11)
        acch2(acc, v0); acch2(acc, v1); acch2(acc, v2); acch2(acc, v3);
    }
    if (nd > 48) {
        A1_SLOT(v0, 12) A1_SLOT(v1, 13) A1_SLOT(v2, 14) A1_SLOT(v3, 15)
        acch2(acc, v0); acch2(acc, v1); acch2(acc, v2); acch2(acc, v3);
    }
    if (d > 64) {                    // rare fallback
        for (int i = 64; i < d; i += 4) {
            int j = i + g;
            uint4 v = make_uint4(0u, 0u, 0u, 0u);
            if (j < d) {
                int c = csr[start + j];
                v = H1h[((unsigned)c << 4) + sl];
            }
            acch2(acc, v);
        }
    }

#pragma unroll
    for (int k = 0; k < 4; ++k) {
        acc[k] = __hadd2(acc[k], h2shfl_xor(acc[k], 16));
        acc[k] = __hadd2(acc[k], h2shfl_xor(acc[k], 32));
    }

    if (g == 0) {
        float f[8];
#pragma unroll
        for (int k = 0; k < 4; ++k) {
            f[2 * k]     = fmaxf(__low2float(acc[k]) * inv, 0.f);
            f[2 * k + 1] = fmaxf(__high2float(acc[k]) * inv, 0.f);
        }
        uint4 o;
        __half2 t0 = __floats2half2_rn(f[0], f[1]);
        __half2 t1 = __floats2half2_rn(f[2], f[3]);
        __half2 t2 = __floats2half2_rn(f[4], f[5]);
        __half2 t3 = __floats2half2_rn(f[6], f[7]);
        o.x = h2bits(t0); o.y = h2bits(t1); o.z = h2bits(t2); o.w = h2bits(t3);
        Hout[(size_t)row * 16 + sl] = o;
    }
}

// agg2: Out[row](fp32) = (1/deg) * sum h2h[c], D=64 (row = 8 uint4, fp16).
// 8-lane groups, packed-fp16 accumulate, 3-round reduce on 4 regs.
#define A2_SLOT(vv, s)                                                      \
    {                                                                       \
        int j = (s) * 8 + g;                                                \
        int c = __shfl(idx, (j < nd) ? j : 0);                              \
        vv = make_uint4(0u, 0u, 0u, 0u);                                    \
        if (j < nd) vv = H2h[((unsigned)c << 3) + sl];                      \
    }

__global__ __launch_bounds__(256) void k_agg2(const uint4* __restrict__ H2h,
                                              const int* __restrict__ offs,
                                              const int* __restrict__ degc,
                                              const float* __restrict__ invdeg,
                                              const int* __restrict__ csr,
                                              float* __restrict__ Out, int n) {
    int wave = threadIdx.x >> 6, lane = threadIdx.x & 63;
    int row = blockIdx.x * 4 + wave;
    if (row >= n) return;
    int start = offs[row], d = degc[row];
    float inv = invdeg[row];
    int g = lane >> 3;       // neighbor slot 0..7
    int sl = lane & 7;       // 16B segment within 128B fp16 row

    int nd = d < 64 ? d : 64;
    int idx = (lane < nd) ? csr[start + lane] : 0;

    __half2 acc[4];
#pragma unroll
    for (int k = 0; k < 4; ++k) acc[k] = h2zero();

    uint4 v0, v1;
    A2_SLOT(v0, 0) A2_SLOT(v1, 1)
    acch2(acc, v0); acch2(acc, v1);
    if (nd > 16) {
        A2_SLOT(v0, 2) A2_SLOT(v1, 3)
        acch2(acc, v0); acch2(acc, v1);
    }
    if (nd > 32) {
        A2_SLOT(v0, 4) A2_SLOT(v1, 5)
        acch2(acc, v0); acch2(acc, v1);
    }
    if (nd > 48) {
        A2_SLOT(v0, 6) A2_SLOT(v1, 7)
        acch2(acc, v0); acch2(acc, v1);
    }
    if (d > 64) {                    // rare fallback
        for (int i = 64; i < d; i += 8) {
            int j = i + g;
            uint4 v = make_uint4(0u, 0u, 0u, 0u);
            if (j < d) {
                int c = csr[start + j];
                v = H2h[((unsigned)c << 3) + sl];
            }
            acch2(acc, v);
        }
    }

#pragma unroll
    for (int k = 0; k < 4; ++k) {
        acc[k] = __hadd2(acc[k], h2shfl_xor(acc[k], 8));
        acc[k] = __hadd2(acc[k], h2shfl_xor(acc[k], 16));
        acc[k] = __hadd2(acc[k], h2shfl_xor(acc[k], 32));
    }

    if (g == 0) {
        float4 o0, o1;
        o0.x = __low2float(acc[0]) * inv;  o0.y = __high2float(acc[0]) * inv;
        o0.z = __low2float(acc[1]) * inv;  o0.w = __high2float(acc[1]) * inv;
        o1.x = __low2float(acc[2]) * inv;  o1.y = __high2float(acc[2]) * inv;
        o1.z = __low2float(acc[3]) * inv;  o1.w = __high2float(acc[3]) * inv;
        ((float4*)Out)[(size_t)row * 16 + sl * 2]     = o0;
        ((float4*)Out)[(size_t)row * 16 + sl * 2 + 1] = o1;
    }
}

extern "C" void kernel_launch(void* const* d_in, const int* in_sizes, int n_in,
                              void* d_out, int out_size, void* d_ws, size_t ws_size,
                              hipStream_t stream) {
    const float* x    = (const float*)d_in[0];
    const float* W1   = (const float*)d_in[1];
    const float* W2   = (const float*)d_in[2];
    const int*   erow = (const int*)d_in[3];
    const int*   ecol = (const int*)d_in[4];
    const int N = in_sizes[0] / DIN;
    const int E = in_sizes[3];

    const int nb  = (N + (1 << BSH) - 1) >> BSH;   // 391 buckets (BSH=8)
    const int nch = (E + CHUNK - 1) / CHUNK;       // 782 chunks (CHUNK=2048)

    size_t o = 0;
    auto take = [&](size_t nbytes) {
        void* p = (char*)d_ws + o;
        o += (nbytes + 255) & ~(size_t)255;
        return p;
    };
    int*            HT     = (int*)take((size_t)nb * nch * 4);
    int*            bsum   = (int*)take((size_t)nb * 4);
    int*            bbase  = (int*)take((size_t)(nb + 1) * 4);
    int*            packed = (int*)take((size_t)E * 4);
    int*            csr    = (int*)take((size_t)E * 4);
    int*            offs   = (int*)take((size_t)N * 4);
    int*            degc   = (int*)take((size_t)N * 4);
    float*          invdeg = (float*)take((size_t)N * 4);
    unsigned short* Wt1    = (unsigned short*)take(128 * 128 * 2);
    unsigned short* Wt2    = (unsigned short*)take(64 * 128 * 2);
    unsigned short* h1h    = (unsigned short*)take((size_t)N * DH * 2);  // fp16
    unsigned*       h      = (unsigned*)take((size_t)N * DH * 2);        // fp16
    unsigned short* h2h    = h1h;   // reuse (dead after agg1); 12.8MB needed

    k_prep      <<<96,  256, 0, stream>>>(W1, W2, Wt1, Wt2);
    k_hist      <<<nch, 256, 0, stream>>>(erow, HT, E, nb, nch);
    k_hscan_row <<<nb,  256, 0, stream>>>(HT, bsum, nch);
    k_hscan_base<<<1,   512, 0, stream>>>(bsum, bbase, nb, E);
    k_part      <<<nch, 256, 0, stream>>>(erow, ecol, HT, bbase, packed, E, nb, nch);
    k_build     <<<nb,  256, 0, stream>>>(packed, bbase, csr, offs, degc, invdeg, N, nb);
    k_gemm1<<<(N + 63) / 64, 256, 0, stream>>>(x, Wt1, h1h, N);
    k_agg1 <<<(N + 3) / 4, 256, 0, stream>>>((const uint4*)h1h, offs, degc, invdeg,
                                             csr, (uint4*)h, N);
    k_gemm2<<<(N + 63) / 64, 256, 0, stream>>>(h, Wt2, h2h, N);
    k_agg2 <<<(N + 3) / 4, 256, 0, stream>>>((const uint4*)h2h, offs, degc,
                                             invdeg, csr, (float*)d_out, N);
}